// Round 6
// baseline (232.497 us; speedup 1.0000x reference)
//
#include <hip/hip_runtime.h>

// ---------------- problem constants ----------------
#define HH 16
#define DD 64
#define SQ 1024          // queries
#define LW 8192          // attention window (keys)
#define OLDK 7168        // old (already-RoPE'd) keys in window
#define CACHE_BASE 2560  // cache row index of window position 0
#define SFRAME 9728      // START_FRAME
#define KSPLIT 8
#define KPER (LW / KSPLIT)   // 1024 keys per split
#define NSTEP (KPER / 64)    // 16 K-steps of 64 keys

// ws layout (bytes)
#define KB_OFF 0u                    // bf16 Kb[h][8192][64]    = 16 MiB
#define VT_OFF 16777216u             // bf16 Vt[h][64][8192]    = 16 MiB
#define QB_OFF 33554432u             // bf16 Qb[h][1024][64]    =  2 MiB
#define OP_OFF 35651584u             // bf16 Op[ks][h][1024][64]= 16 MiB
#define LP_OFF 69206016u             // f32  Lp[ks][h][1024]    = 512 KiB

typedef __bf16 bf16x8 __attribute__((ext_vector_type(8)));
typedef float floatx16 __attribute__((ext_vector_type(16)));
typedef float floatx2 __attribute__((ext_vector_type(2)));
typedef unsigned uintx2 __attribute__((ext_vector_type(2)));
typedef unsigned uintx4 __attribute__((ext_vector_type(4)));

__device__ __forceinline__ unsigned short f2bf(float f) {
  unsigned u = __builtin_bit_cast(unsigned, f);
  u += 0x7fffu + ((u >> 16) & 1u);           // RNE
  return (unsigned short)(u >> 16);
}

__device__ __forceinline__ float fast_exp2(float x) {
#if __has_builtin(__builtin_amdgcn_exp2f)
  return __builtin_amdgcn_exp2f(x);
#else
  return __builtin_exp2f(x);
#endif
}

// pack two f32 -> bf16x2 (as uint). element0 = a (low 16), element1 = b.
__device__ __forceinline__ unsigned pack_bf2(float a, float b) {
#if __has_builtin(__builtin_amdgcn_cvt_pk_bf16_f32)
  typedef __bf16 bf16x2_t __attribute__((ext_vector_type(2)));
  bf16x2_t r = __builtin_amdgcn_cvt_pk_bf16_f32(a, b);
  return __builtin_bit_cast(unsigned, r);
#else
  unsigned ua = __builtin_bit_cast(unsigned, a) + 0x8000u;  // round-half-up
  unsigned ub = __builtin_bit_cast(unsigned, b) + 0x8000u;
  return __builtin_amdgcn_perm(ub, ua, 0x07060302);         // [ua.hi16 | ub.hi16]
#endif
}

__device__ __forceinline__ void async16(void* lds, const void* g) {
  __builtin_amdgcn_global_load_lds((__attribute__((address_space(1))) void*)(g),
                                   (__attribute__((address_space(3))) void*)(lds),
                                   16, 0, 0);
}

// ---------------- prepass: build bf16 Kb / Vt(transposed) / Qb(rope*scale) ----
// R5 layout kept: 4 units/block in copy/rope branches (ILP), bf16 LDS tile.
__global__ __launch_bounds__(256) void prepass(
    const float* __restrict__ qin, const float* __restrict__ kin,
    const float* __restrict__ vin, const float* __restrict__ ck,
    const float* __restrict__ cv, const float* __restrict__ fc,
    const float* __restrict__ fs, unsigned short* __restrict__ Kb,
    unsigned short* __restrict__ Vt, unsigned short* __restrict__ Qb) {
  __shared__ unsigned short tl[128 * 66];
  int b = blockIdx.x, t = threadIdx.x;
  if (b < 1024) {
    // V transpose: 128kk x 64d tile -> Vt[h][d][kk], bf16 in LDS
    int h = b >> 6, kk0 = (b & 63) * 128;
    int c = t & 15;
#pragma unroll
    for (int it = 0; it < 8; it++) {
      int kk = it * 16 + (t >> 4);
      int gk = kk0 + kk;
      const float* src = (gk < OLDK)
                             ? cv + (CACHE_BASE + gk) * (HH * DD) + h * DD + 4 * c
                             : vin + (gk - OLDK) * (HH * DD) + h * DD + 4 * c;
      float4 vv = *(const float4*)src;
      ushort2 p0, p1;
      p0.x = f2bf(vv.x); p0.y = f2bf(vv.y);
      p1.x = f2bf(vv.z); p1.y = f2bf(vv.w);
      *(ushort2*)(tl + kk * 66 + 4 * c) = p0;
      *(ushort2*)(tl + kk * 66 + 4 * c + 2) = p1;
    }
    __syncthreads();
    int kq = t & 15;
#pragma unroll
    for (int jt = 0; jt < 4; jt++) {
      int d = jt * 16 + (t >> 4);
      ushort4 lo, hi;
      unsigned short tmp[8];
#pragma unroll
      for (int j = 0; j < 8; j++) {
        int kk = 8 * kq + j;
        tmp[j] = tl[kk * 66 + d];
      }
      lo.x = tmp[0]; lo.y = tmp[1]; lo.z = tmp[2]; lo.w = tmp[3];
      hi.x = tmp[4]; hi.y = tmp[5]; hi.z = tmp[6]; hi.w = tmp[7];
      unsigned short* dst = Vt + (h * DD + d) * LW + kk0 + 8 * kq;
      *(ushort4*)(dst) = lo;
      *(ushort4*)(dst + 4) = hi;
    }
  } else if (b < 2816) {
    // K copy (old keys): 1792 blocks, 64 consecutive kk rows each.
    int n = b - 1024;
    int h = n / 112;                 // 112 blocks per h * 64 kk = 7168 kk
    int kkb = (n % 112) * 64;
    int lane = t & 15;
    const float* basein = ck + h * DD + lane * 4;
    unsigned short* baseout = Kb + h * (LW * DD) + lane * 4;
#pragma unroll
    for (int i = 0; i < 4; i++) {
      int kk = kkb + i * 16 + (t >> 4);
      float4 val = *(const float4*)(basein + (CACHE_BASE + kk) * (HH * DD));
      ushort4 o;
      o.x = f2bf(val.x); o.y = f2bf(val.y); o.z = f2bf(val.z); o.w = f2bf(val.w);
      *(ushort4*)(baseout + kk * DD) = o;
    }
  } else if (b < 3328) {
    // K rope (new keys): 512 blocks, 4 old units each
    int m = b - 2816;
#pragma unroll
    for (int u = 0; u < 4; u++) {
      int rh = (4 * m + u) * 8 + (t >> 5);
      int s = rh >> 4, h = rh & 15, i = t & 31;
      float2 x = *(const float2*)(kin + s * (HH * DD) + h * DD + 2 * i);
      float c = fc[(SFRAME + s) * DD + 2 * i];
      float sn = fs[(SFRAME + s) * DD + 2 * i];
      ushort2 o;
      o.x = f2bf(x.x * c - x.y * sn);
      o.y = f2bf(x.y * c + x.x * sn);
      *(ushort2*)(Kb + (h * LW + OLDK + s) * DD + 2 * i) = o;
    }
  } else {
    // Q rope + fold (1/sqrt(D)) * log2(e): 512 blocks, 4 old units each
    int m = b - 3328;
    const float SC = 0.18033688011112042f;  // 0.125 * log2(e)
#pragma unroll
    for (int u = 0; u < 4; u++) {
      int rh = (4 * m + u) * 8 + (t >> 5);
      int s = rh >> 4, h = rh & 15, i = t & 31;
      float2 x = *(const float2*)(qin + s * (HH * DD) + h * DD + 2 * i);
      float c = fc[(SFRAME + s) * DD + 2 * i];
      float sn = fs[(SFRAME + s) * DD + 2 * i];
      ushort2 o;
      o.x = f2bf((x.x * c - x.y * sn) * SC);
      o.y = f2bf((x.y * c + x.x * sn) * SC);
      *(ushort2*)(Qb + (h * SQ + s) * DD + 2 * i) = o;
    }
  }
}

// ---------------- flash attention (no-max exp2 softmax, K-split 8) -----------
// R6 revision: 2 tiles (128 keys) per barrier interval. The per-step neither-
// pipe stall (~3600 cyc/SIMD/step) survived occupancy/vmcnt/VALU/PV-defer
// experiments; the untouched per-interval costs are the barrier ramp and the
// cold ds_read->MFMA restart. 4 LDS buffer pairs (64 KiB, 2 blocks/CU =
// 128 KiB <= 160) let each interval compute two tiles back-to-back with NO
// barrier between them -- the second tile's ds_reads overlap the first tile's
// PV MFMAs, and the barrier count halves (16 -> 8).
__global__ __launch_bounds__(256, 2) void attn(
    const unsigned short* __restrict__ Kb, const unsigned short* __restrict__ Vt,
    const unsigned short* __restrict__ Qb, unsigned short* __restrict__ Op,
    float* __restrict__ Lp) {
  __shared__ __align__(16) unsigned char sK[4][8192];  // 64kk x 64d bf16, swizzled granules
  __shared__ __align__(16) unsigned char sV[4][8192];  // 64d x 64kk bf16, swizzled granules

  int bid = blockIdx.x;
  int g = bid & 127, qb = bid >> 7;
  int h = g & 15, ks = g >> 4;
  int t = threadIdx.x;
  int w = t >> 6, lane = t & 63;
  int l31 = lane & 31, e = lane >> 5;
  int q0 = qb * 256 + w * 64;

  // granule-position bases for the XOR swizzle (rows l31 and l31+32)
  int baseA = (l31 & 7) ^ ((l31 >> 3) & 7);
  int baseB = (l31 & 7) ^ (((l31 >> 3) + 4) & 7);

  // hoisted Q B-fragments, 2 q-tiles x 4 d-slices: B[k=d][n=q], n=l31, k=16c+8e+j
  bf16x8 qf[2][4];
#pragma unroll
  for (int tq = 0; tq < 2; tq++) {
    const unsigned short* qptr = Qb + (h * SQ + q0 + 32 * tq + l31) * DD + 8 * e;
#pragma unroll
    for (int c = 0; c < 4; c++) qf[tq][c] = *(const bf16x8*)(qptr + 16 * c);
  }

  floatx16 o[2][2];   // [tq][d-half], O^T[d][q]
#pragma unroll
  for (int a = 0; a < 2; a++)
#pragma unroll
    for (int bb = 0; bb < 2; bb++)
#pragma unroll
      for (int i = 0; i < 16; i++) o[a][bb][i] = 0.f;
  float ls[2] = {0.f, 0.f};

  const floatx16 fz = {0.f};   // hoisted zero C-operand for QK chains

  const unsigned short* KbH = Kb + h * (LW * DD);
  const unsigned short* VtH = Vt + h * (DD * LW);
  int kkBase = ks * KPER;

  // ---- hoisted staging state (step-invariant swizzle/addresses) ----
  int gi0 = w * 128 + lane;            // hf = 0
  int gi1 = gi0 + 64;                  // hf = 1
  int rr0 = gi0 >> 3, rr1 = gi1 >> 3;  // kk for K, d for V
  int sw0 = (gi0 & 7) ^ (rr0 & 7) ^ ((rr0 >> 3) & 7);
  int sw1 = (gi1 & 7) ^ (rr1 & 7) ^ ((rr1 >> 3) & 7);
  const unsigned short* gK0 = KbH + (kkBase + rr0) * DD + sw0 * 8;
  const unsigned short* gK1 = KbH + (kkBase + rr1) * DD + sw1 * 8;
  const unsigned short* gV0 = VtH + rr0 * LW + kkBase + sw0 * 8;
  const unsigned short* gV1 = VtH + rr1 * LW + kkBase + sw1 * 8;
  int d0 = gi0 * 16, d1 = gi1 * 16;    // LDS dest byte offsets (fixed)

  // stage the NEXT sequential 64kk tile into (bK,bV); advances pointers.
  auto stage = [&](unsigned char* bK, unsigned char* bV) {
    async16(bK + d0, gK0);
    async16(bV + d0, gV0);
    async16(bK + d1, gK1);
    async16(bV + d1, gV1);
    gK0 += 64 * DD; gK1 += 64 * DD;
    gV0 += 64;      gV1 += 64;
  };

  // softmax of one 32kk half: exp2, packed row-sum, pack, C->B layout swap.
  auto softmax_half = [&](floatx16& sv, int tq, int tk, bf16x8 pf[2][4]) {
#pragma unroll
    for (int i = 0; i < 16; i++) sv[i] = fast_exp2(sv[i]);
    floatx2 t0, t1, t2, t3;
    t0[0] = sv[0];  t0[1] = sv[1];
    t1[0] = sv[2];  t1[1] = sv[3];
    t2[0] = sv[4];  t2[1] = sv[5];
    t3[0] = sv[6];  t3[1] = sv[7];
    floatx2 u0 = t0 + t1, u1 = t2 + t3;
    floatx2 t4, t5, t6, t7;
    t4[0] = sv[8];  t4[1] = sv[9];
    t5[0] = sv[10]; t5[1] = sv[11];
    t6[0] = sv[12]; t6[1] = sv[13];
    t7[0] = sv[14]; t7[1] = sv[15];
    floatx2 u2 = t4 + t5, u3 = t6 + t7;
    floatx2 v0 = u0 + u1, v1 = u2 + u3;
    floatx2 vs = v0 + v1;
    ls[tq] += vs[0] + vs[1];
#pragma unroll
    for (int kcp = 0; kcp < 2; kcp++) {
      unsigned u0p = pack_bf2(sv[8 * kcp + 0], sv[8 * kcp + 1]);
      unsigned u1p = pack_bf2(sv[8 * kcp + 2], sv[8 * kcp + 3]);
      unsigned u2p = pack_bf2(sv[8 * kcp + 4], sv[8 * kcp + 5]);
      unsigned u3p = pack_bf2(sv[8 * kcp + 6], sv[8 * kcp + 7]);
      uintx2 r0 = __builtin_amdgcn_permlane32_swap(u0p, u2p, false, false);
      uintx2 r1 = __builtin_amdgcn_permlane32_swap(u1p, u3p, false, false);
      uintx4 f;
      f[0] = r0[0]; f[1] = r1[0]; f[2] = r0[1]; f[3] = r1[1];
      pf[tq][2 * tk + kcp] = __builtin_bit_cast(bf16x8, f);
    }
  };

  // one K-step: compute on (cK,cV); optionally stage next tile into (nK,nV)
  auto step = [&](const unsigned char* cK, const unsigned char* cV,
                  bool doStage, unsigned char* nK, unsigned char* nV) {
    bf16x8 pf[2][4];   // [tq][kc_global] P in B-operand layout

    // phase 1: QK tk=0 (kk rows [0,32), swizzle baseA); c=0 peeled with zero C
    floatx16 sA0, sA1;
    {
      int p0 = e ^ baseA;
      bf16x8 ka0 = *(const bf16x8*)(cK + (l31 * 8 + p0) * 16);
      sA0 = __builtin_amdgcn_mfma_f32_32x32x16_bf16(ka0, qf[0][0], fz, 0, 0, 0);
      sA1 = __builtin_amdgcn_mfma_f32_32x32x16_bf16(ka0, qf[1][0], fz, 0, 0, 0);
#pragma unroll
      for (int c = 1; c < 4; c++) {
        int p = (2 * c + e) ^ baseA;
        bf16x8 ka = *(const bf16x8*)(cK + (l31 * 8 + p) * 16);
        sA0 = __builtin_amdgcn_mfma_f32_32x32x16_bf16(ka, qf[0][c], sA0, 0, 0, 0);
        sA1 = __builtin_amdgcn_mfma_f32_32x32x16_bf16(ka, qf[1][c], sA1, 0, 0, 0);
      }
    }

    // prefetch during compute: addressing is 4 pointer bumps; loads land
    // before the next barrier's implicit vmcnt(0).
    if (doStage) stage(nK, nV);

    // phase 2: QK tk=1 (kk rows [32,64), swizzle baseB)  -- matrix pipe
    floatx16 sB0, sB1;
    {
      int p0 = e ^ baseB;
      bf16x8 kb0 = *(const bf16x8*)(cK + ((l31 + 32) * 8 + p0) * 16);
      sB0 = __builtin_amdgcn_mfma_f32_32x32x16_bf16(kb0, qf[0][0], fz, 0, 0, 0);
      sB1 = __builtin_amdgcn_mfma_f32_32x32x16_bf16(kb0, qf[1][0], fz, 0, 0, 0);
#pragma unroll
      for (int c = 1; c < 4; c++) {
        int p = (2 * c + e) ^ baseB;
        bf16x8 kb = *(const bf16x8*)(cK + ((l31 + 32) * 8 + p) * 16);
        sB0 = __builtin_amdgcn_mfma_f32_32x32x16_bf16(kb, qf[0][c], sB0, 0, 0, 0);
        sB1 = __builtin_amdgcn_mfma_f32_32x32x16_bf16(kb, qf[1][c], sB1, 0, 0, 0);
      }
    }

    // phase 3: softmax tk=0 (VALU -- overlaps phase-2 MFMAs)
    softmax_half(sA0, 0, 0, pf);
    softmax_half(sA1, 1, 0, pf);

    // phase 4: PV kc=0,1 (uses pf[*][0..1] only)  -- matrix pipe
#pragma unroll
    for (int kc = 0; kc < 2; kc++) {
      int pA = (2 * kc + e) ^ baseA;
      int pB = (2 * kc + e) ^ baseB;
      bf16x8 va = *(const bf16x8*)(cV + (l31 * 8 + pA) * 16);
      bf16x8 vb = *(const bf16x8*)(cV + ((l31 + 32) * 8 + pB) * 16);
      o[0][0] = __builtin_amdgcn_mfma_f32_32x32x16_bf16(va, pf[0][kc], o[0][0], 0, 0, 0);
      o[0][1] = __builtin_amdgcn_mfma_f32_32x32x16_bf16(vb, pf[0][kc], o[0][1], 0, 0, 0);
      o[1][0] = __builtin_amdgcn_mfma_f32_32x32x16_bf16(va, pf[1][kc], o[1][0], 0, 0, 0);
      o[1][1] = __builtin_amdgcn_mfma_f32_32x32x16_bf16(vb, pf[1][kc], o[1][1], 0, 0, 0);
    }

    // phase 5: softmax tk=1 (VALU -- overlaps phase-4 MFMAs)
    softmax_half(sB0, 0, 1, pf);
    softmax_half(sB1, 1, 1, pf);

    // phase 6: PV kc=2,3
#pragma unroll
    for (int kc = 2; kc < 4; kc++) {
      int pA = (2 * kc + e) ^ baseA;
      int pB = (2 * kc + e) ^ baseB;
      bf16x8 va = *(const bf16x8*)(cV + (l31 * 8 + pA) * 16);
      bf16x8 vb = *(const bf16x8*)(cV + ((l31 + 32) * 8 + pB) * 16);
      o[0][0] = __builtin_amdgcn_mfma_f32_32x32x16_bf16(va, pf[0][kc], o[0][0], 0, 0, 0);
      o[0][1] = __builtin_amdgcn_mfma_f32_32x32x16_bf16(vb, pf[0][kc], o[0][1], 0, 0, 0);
      o[1][0] = __builtin_amdgcn_mfma_f32_32x32x16_bf16(va, pf[1][kc], o[1][0], 0, 0, 0);
      o[1][1] = __builtin_amdgcn_mfma_f32_32x32x16_bf16(vb, pf[1][kc], o[1][1], 0, 0, 0);
    }
  };

  // prologue: stage tiles 0,1 into buffer pairs 0,1
  stage(sK[0], sV[0]);
  stage(sK[1], sV[1]);

  // 4 iterations x 2 barrier intervals x 2 tiles = 16 tiles.
  // Interval A computes bufs {0,1} (tiles 4m,4m+1), stages tiles 4m+2,4m+3
  // into bufs {2,3}; interval B computes {2,3}, stages 4m+4,4m+5 into {0,1}.
  for (int m = 0; m < 4; m++) {
    __syncthreads();                               // bufs 0,1 ready; 2,3 free
    step(sK[0], sV[0], true, sK[2], sV[2]);        // tile 4m+0; stage 4m+2
    step(sK[1], sV[1], true, sK[3], sV[3]);        // tile 4m+1; stage 4m+3
    __syncthreads();                               // bufs 2,3 ready; 0,1 free
    bool more = m < 3;
    step(sK[2], sV[2], more, sK[0], sV[0]);        // tile 4m+2; stage 4m+4
    step(sK[3], sV[3], more, sK[1], sV[1]);        // tile 4m+3; stage 4m+5
  }

  // epilogue: store split numerators (bf16) + denominators (f32)
#pragma unroll
  for (int tq = 0; tq < 2; tq++) {
    float l = ls[tq];
    l += __shfl_xor(l, 32, 64);
    int qrow = q0 + 32 * tq + l31;
    unsigned short* op = Op + (((ks * 16 + h) * SQ) + qrow) * DD;
#pragma unroll
    for (int t4 = 0; t4 < 4; t4++) {
      uint2 a, b;
      a.x = pack_bf2(o[tq][0][4 * t4 + 0], o[tq][0][4 * t4 + 1]);
      a.y = pack_bf2(o[tq][0][4 * t4 + 2], o[tq][0][4 * t4 + 3]);
      b.x = pack_bf2(o[tq][1][4 * t4 + 0], o[tq][1][4 * t4 + 1]);
      b.y = pack_bf2(o[tq][1][4 * t4 + 2], o[tq][1][4 * t4 + 3]);
      *(uint2*)(op + 8 * t4 + 4 * e) = a;         // d = 8t4+4e+0..3
      *(uint2*)(op + 32 + 8 * t4 + 4 * e) = b;    // d = 32+8t4+4e+0..3
    }
    if (e == 0) Lp[(ks * 16 + h) * SQ + qrow] = l;
  }
}

// ---------------- combine splits (bf16 numerators, 8 d per thread) -----------
__global__ __launch_bounds__(256) void combine(const unsigned short* __restrict__ Op,
                                               const float* __restrict__ Lp,
                                               float* __restrict__ out) {
  int idx = blockIdx.x * 256 + threadIdx.x;     // 131072 threads
  int d8 = idx & 7, q = (idx >> 3) & 1023, h = idx >> 13;
  float num[8] = {0.f, 0.f, 0.f, 0.f, 0.f, 0.f, 0.f, 0.f};
  float den = 0.f;
#pragma unroll
  for (int s = 0; s < KSPLIT; s++) {
    int row = (s * 16 + h) * SQ + q;
    uint4 pkv = *(const uint4*)(Op + row * DD + 8 * d8);
    num[0] += __builtin_bit_cast(float, pkv.x << 16);
    num[1] += __builtin_bit_cast(float, pkv.x & 0xffff0000u);
    num[2] += __builtin_bit_cast(float, pkv.y << 16);
    num[3] += __builtin_bit_cast(float, pkv.y & 0xffff0000u);
    num[4] += __builtin_bit_cast(float, pkv.z << 16);
    num[5] += __builtin_bit_cast(float, pkv.z & 0xffff0000u);
    num[6] += __builtin_bit_cast(float, pkv.w << 16);
    num[7] += __builtin_bit_cast(float, pkv.w & 0xffff0000u);
    den += Lp[row];
  }
  float r = 1.0f / den;
  float* op = out + q * (HH * DD) + h * DD + 8 * d8;
  float4 a, bq;
  a.x = num[0] * r; a.y = num[1] * r; a.z = num[2] * r; a.w = num[3] * r;
  bq.x = num[4] * r; bq.y = num[5] * r; bq.z = num[6] * r; bq.w = num[7] * r;
  *(float4*)(op) = a;
  *(float4*)(op + 4) = bq;
}

extern "C" void kernel_launch(void* const* d_in, const int* in_sizes, int n_in,
                              void* d_out, int out_size, void* d_ws, size_t ws_size,
                              hipStream_t stream) {
  const float* q  = (const float*)d_in[0];
  const float* k  = (const float*)d_in[1];
  const float* v  = (const float*)d_in[2];
  const float* ck = (const float*)d_in[3];
  const float* cv = (const float*)d_in[4];
  const float* fc = (const float*)d_in[5];
  const float* fs = (const float*)d_in[6];
  float* out = (float*)d_out;
  char* ws = (char*)d_ws;

  unsigned short* Kb = (unsigned short*)(ws + KB_OFF);
  unsigned short* Vt = (unsigned short*)(ws + VT_OFF);
  unsigned short* Qb = (unsigned short*)(ws + QB_OFF);
  unsigned short* Op = (unsigned short*)(ws + OP_OFF);
  float* Lp = (float*)(ws + LP_OFF);

  prepass<<<3840, 256, 0, stream>>>(q, k, v, ck, cv, fc, fs, Kb, Vt, Qb);
  attn<<<512, 256, 0, stream>>>(Kb, Vt, Qb, Op, Lp);
  combine<<<512, 256, 0, stream>>>(Op, Lp, out);
}

// Round 7
// 170.743 us; speedup vs baseline: 1.3617x; 1.3617x over previous
//
#include <hip/hip_runtime.h>

// ---------------- problem constants ----------------
#define HH 16
#define DD 64
#define SQ 1024          // queries
#define LW 8192          // attention window (keys)
#define OLDK 7168        // old (already-RoPE'd) keys in window
#define CACHE_BASE 2560  // cache row index of window position 0
#define SFRAME 9728      // START_FRAME
#define KSPLIT 8
#define KPER (LW / KSPLIT)   // 1024 keys per split
#define NSTEP (KPER / 64)    // 16 K-steps of 64 keys

// ws layout (bytes)
#define KB_OFF 0u                    // bf16 Kb[h][8192][64]    = 16 MiB
#define VT_OFF 16777216u             // bf16 Vt[h][64][8192]    = 16 MiB
#define QB_OFF 33554432u             // bf16 Qb[h][1024][64]    =  2 MiB
#define OP_OFF 35651584u             // bf16 Op[ks][h][1024][64]= 16 MiB
#define LP_OFF 69206016u             // f32  Lp[ks][h][1024]    = 512 KiB

typedef __bf16 bf16x8 __attribute__((ext_vector_type(8)));
typedef float floatx16 __attribute__((ext_vector_type(16)));
typedef float floatx2 __attribute__((ext_vector_type(2)));
typedef unsigned uintx2 __attribute__((ext_vector_type(2)));
typedef unsigned uintx4 __attribute__((ext_vector_type(4)));

__device__ __forceinline__ unsigned short f2bf(float f) {
  unsigned u = __builtin_bit_cast(unsigned, f);
  u += 0x7fffu + ((u >> 16) & 1u);           // RNE
  return (unsigned short)(u >> 16);
}

__device__ __forceinline__ float fast_exp2(float x) {
#if __has_builtin(__builtin_amdgcn_exp2f)
  return __builtin_amdgcn_exp2f(x);
#else
  return __builtin_exp2f(x);
#endif
}

// pack two f32 -> bf16x2 (as uint). element0 = a (low 16), element1 = b.
__device__ __forceinline__ unsigned pack_bf2(float a, float b) {
#if __has_builtin(__builtin_amdgcn_cvt_pk_bf16_f32)
  typedef __bf16 bf16x2_t __attribute__((ext_vector_type(2)));
  bf16x2_t r = __builtin_amdgcn_cvt_pk_bf16_f32(a, b);
  return __builtin_bit_cast(unsigned, r);
#else
  unsigned ua = __builtin_bit_cast(unsigned, a) + 0x8000u;  // round-half-up
  unsigned ub = __builtin_bit_cast(unsigned, b) + 0x8000u;
  return __builtin_amdgcn_perm(ub, ua, 0x07060302);         // [ua.hi16 | ub.hi16]
#endif
}

__device__ __forceinline__ void async16(void* lds, const void* g) {
  __builtin_amdgcn_global_load_lds((__attribute__((address_space(1))) void*)(g),
                                   (__attribute__((address_space(3))) void*)(lds),
                                   16, 0, 0);
}

// ---------------- prepass: build bf16 Kb / Vt(transposed) / Qb(rope*scale) ----
// R5: per-thread ILP. The copy/rope branches give each thread 4 independent
// load->cvt->store chains (grid 3840); bf16 LDS transpose tile (16.9 KB).
__global__ __launch_bounds__(256) void prepass(
    const float* __restrict__ qin, const float* __restrict__ kin,
    const float* __restrict__ vin, const float* __restrict__ ck,
    const float* __restrict__ cv, const float* __restrict__ fc,
    const float* __restrict__ fs, unsigned short* __restrict__ Kb,
    unsigned short* __restrict__ Vt, unsigned short* __restrict__ Qb) {
  __shared__ unsigned short tl[128 * 66];
  int b = blockIdx.x, t = threadIdx.x;
  if (b < 1024) {
    // V transpose: 128kk x 64d tile -> Vt[h][d][kk], bf16 in LDS
    int h = b >> 6, kk0 = (b & 63) * 128;
    int c = t & 15;
#pragma unroll
    for (int it = 0; it < 8; it++) {
      int kk = it * 16 + (t >> 4);
      int gk = kk0 + kk;
      const float* src = (gk < OLDK)
                             ? cv + (CACHE_BASE + gk) * (HH * DD) + h * DD + 4 * c
                             : vin + (gk - OLDK) * (HH * DD) + h * DD + 4 * c;
      float4 vv = *(const float4*)src;
      ushort2 p0, p1;
      p0.x = f2bf(vv.x); p0.y = f2bf(vv.y);
      p1.x = f2bf(vv.z); p1.y = f2bf(vv.w);
      *(ushort2*)(tl + kk * 66 + 4 * c) = p0;
      *(ushort2*)(tl + kk * 66 + 4 * c + 2) = p1;
    }
    __syncthreads();
    int kq = t & 15;
#pragma unroll
    for (int jt = 0; jt < 4; jt++) {
      int d = jt * 16 + (t >> 4);
      ushort4 lo, hi;
      unsigned short tmp[8];
#pragma unroll
      for (int j = 0; j < 8; j++) {
        int kk = 8 * kq + j;
        tmp[j] = tl[kk * 66 + d];
      }
      lo.x = tmp[0]; lo.y = tmp[1]; lo.z = tmp[2]; lo.w = tmp[3];
      hi.x = tmp[4]; hi.y = tmp[5]; hi.z = tmp[6]; hi.w = tmp[7];
      unsigned short* dst = Vt + (h * DD + d) * LW + kk0 + 8 * kq;
      *(ushort4*)(dst) = lo;
      *(ushort4*)(dst + 4) = hi;
    }
  } else if (b < 2816) {
    // K copy (old keys): 1792 blocks, 64 consecutive kk rows each.
    int n = b - 1024;
    int h = n / 112;                 // 112 blocks per h * 64 kk = 7168 kk
    int kkb = (n % 112) * 64;
    int lane = t & 15;
    const float* basein = ck + h * DD + lane * 4;
    unsigned short* baseout = Kb + h * (LW * DD) + lane * 4;
#pragma unroll
    for (int i = 0; i < 4; i++) {
      int kk = kkb + i * 16 + (t >> 4);
      float4 val = *(const float4*)(basein + (CACHE_BASE + kk) * (HH * DD));
      ushort4 o;
      o.x = f2bf(val.x); o.y = f2bf(val.y); o.z = f2bf(val.z); o.w = f2bf(val.w);
      *(ushort4*)(baseout + kk * DD) = o;
    }
  } else if (b < 3328) {
    // K rope (new keys): 512 blocks, 4 old units each
    int m = b - 2816;
#pragma unroll
    for (int u = 0; u < 4; u++) {
      int rh = (4 * m + u) * 8 + (t >> 5);
      int s = rh >> 4, h = rh & 15, i = t & 31;
      float2 x = *(const float2*)(kin + s * (HH * DD) + h * DD + 2 * i);
      float c = fc[(SFRAME + s) * DD + 2 * i];
      float sn = fs[(SFRAME + s) * DD + 2 * i];
      ushort2 o;
      o.x = f2bf(x.x * c - x.y * sn);
      o.y = f2bf(x.y * c + x.x * sn);
      *(ushort2*)(Kb + (h * LW + OLDK + s) * DD + 2 * i) = o;
    }
  } else {
    // Q rope + fold (1/sqrt(D)) * log2(e): 512 blocks, 4 old units each
    int m = b - 3328;
    const float SC = 0.18033688011112042f;  // 0.125 * log2(e)
#pragma unroll
    for (int u = 0; u < 4; u++) {
      int rh = (4 * m + u) * 8 + (t >> 5);
      int s = rh >> 4, h = rh & 15, i = t & 31;
      float2 x = *(const float2*)(qin + s * (HH * DD) + h * DD + 2 * i);
      float c = fc[(SFRAME + s) * DD + 2 * i];
      float sn = fs[(SFRAME + s) * DD + 2 * i];
      ushort2 o;
      o.x = f2bf((x.x * c - x.y * sn) * SC);
      o.y = f2bf((x.y * c + x.x * sn) * SC);
      *(ushort2*)(Qb + (h * SQ + s) * DD + 2 * i) = o;
    }
  }
}

// ---------------- flash attention (no-max exp2 softmax, K-split 8) -----------
// R3/R5 structure (best measured: 47.0-47.5us attn, no spill, VGPR 120).
// 2-buffer, __syncthreads, 64q/wave, hoisted staging pointers, unroll-by-2.
// Validated local optimum: occupancy x2 (R1), counted-vmcnt ring (R2),
// PV-deferral (R4), 2-tile intervals (R6, spilled) all regressed or nulled.
__global__ __launch_bounds__(256, 2) void attn(
    const unsigned short* __restrict__ Kb, const unsigned short* __restrict__ Vt,
    const unsigned short* __restrict__ Qb, unsigned short* __restrict__ Op,
    float* __restrict__ Lp) {
  __shared__ __align__(16) unsigned char sK[2][8192];  // 64kk x 64d bf16, swizzled granules
  __shared__ __align__(16) unsigned char sV[2][8192];  // 64d x 64kk bf16, swizzled granules

  int bid = blockIdx.x;
  int g = bid & 127, qb = bid >> 7;
  int h = g & 15, ks = g >> 4;
  int t = threadIdx.x;
  int w = t >> 6, lane = t & 63;
  int l31 = lane & 31, e = lane >> 5;
  int q0 = qb * 256 + w * 64;

  // granule-position bases for the XOR swizzle (rows l31 and l31+32)
  int baseA = (l31 & 7) ^ ((l31 >> 3) & 7);
  int baseB = (l31 & 7) ^ (((l31 >> 3) + 4) & 7);

  // hoisted Q B-fragments, 2 q-tiles x 4 d-slices: B[k=d][n=q], n=l31, k=16c+8e+j
  bf16x8 qf[2][4];
#pragma unroll
  for (int tq = 0; tq < 2; tq++) {
    const unsigned short* qptr = Qb + (h * SQ + q0 + 32 * tq + l31) * DD + 8 * e;
#pragma unroll
    for (int c = 0; c < 4; c++) qf[tq][c] = *(const bf16x8*)(qptr + 16 * c);
  }

  floatx16 o[2][2];   // [tq][d-half], O^T[d][q]
#pragma unroll
  for (int a = 0; a < 2; a++)
#pragma unroll
    for (int bb = 0; bb < 2; bb++)
#pragma unroll
      for (int i = 0; i < 16; i++) o[a][bb][i] = 0.f;
  float ls[2] = {0.f, 0.f};

  const floatx16 fz = {0.f};   // hoisted zero C-operand for QK chains

  const unsigned short* KbH = Kb + h * (LW * DD);
  const unsigned short* VtH = Vt + h * (DD * LW);
  int kkBase = ks * KPER;

  // ---- hoisted staging state (step-invariant swizzle/addresses) ----
  int gi0 = w * 128 + lane;            // hf = 0
  int gi1 = gi0 + 64;                  // hf = 1
  int rr0 = gi0 >> 3, rr1 = gi1 >> 3;  // kk for K, d for V
  int sw0 = (gi0 & 7) ^ (rr0 & 7) ^ ((rr0 >> 3) & 7);
  int sw1 = (gi1 & 7) ^ (rr1 & 7) ^ ((rr1 >> 3) & 7);
  const unsigned short* gK0 = KbH + (kkBase + rr0) * DD + sw0 * 8;
  const unsigned short* gK1 = KbH + (kkBase + rr1) * DD + sw1 * 8;
  const unsigned short* gV0 = VtH + rr0 * LW + kkBase + sw0 * 8;
  const unsigned short* gV1 = VtH + rr1 * LW + kkBase + sw1 * 8;
  int d0 = gi0 * 16, d1 = gi1 * 16;    // LDS dest byte offsets (fixed)

  // stage the NEXT sequential 64kk tile into (bK,bV); advances pointers.
  auto stage = [&](unsigned char* bK, unsigned char* bV) {
    async16(bK + d0, gK0);
    async16(bV + d0, gV0);
    async16(bK + d1, gK1);
    async16(bV + d1, gV1);
    gK0 += 64 * DD; gK1 += 64 * DD;
    gV0 += 64;      gV1 += 64;
  };

  // softmax of one 32kk half: exp2, packed row-sum, pack, C->B layout swap.
  auto softmax_half = [&](floatx16& sv, int tq, int tk, bf16x8 pf[2][4]) {
#pragma unroll
    for (int i = 0; i < 16; i++) sv[i] = fast_exp2(sv[i]);
    floatx2 t0, t1, t2, t3;
    t0[0] = sv[0];  t0[1] = sv[1];
    t1[0] = sv[2];  t1[1] = sv[3];
    t2[0] = sv[4];  t2[1] = sv[5];
    t3[0] = sv[6];  t3[1] = sv[7];
    floatx2 u0 = t0 + t1, u1 = t2 + t3;
    floatx2 t4, t5, t6, t7;
    t4[0] = sv[8];  t4[1] = sv[9];
    t5[0] = sv[10]; t5[1] = sv[11];
    t6[0] = sv[12]; t6[1] = sv[13];
    t7[0] = sv[14]; t7[1] = sv[15];
    floatx2 u2 = t4 + t5, u3 = t6 + t7;
    floatx2 v0 = u0 + u1, v1 = u2 + u3;
    floatx2 vs = v0 + v1;
    ls[tq] += vs[0] + vs[1];
#pragma unroll
    for (int kcp = 0; kcp < 2; kcp++) {
      unsigned u0p = pack_bf2(sv[8 * kcp + 0], sv[8 * kcp + 1]);
      unsigned u1p = pack_bf2(sv[8 * kcp + 2], sv[8 * kcp + 3]);
      unsigned u2p = pack_bf2(sv[8 * kcp + 4], sv[8 * kcp + 5]);
      unsigned u3p = pack_bf2(sv[8 * kcp + 6], sv[8 * kcp + 7]);
      uintx2 r0 = __builtin_amdgcn_permlane32_swap(u0p, u2p, false, false);
      uintx2 r1 = __builtin_amdgcn_permlane32_swap(u1p, u3p, false, false);
      uintx4 f;
      f[0] = r0[0]; f[1] = r1[0]; f[2] = r0[1]; f[3] = r1[1];
      pf[tq][2 * tk + kcp] = __builtin_bit_cast(bf16x8, f);
    }
  };

  // one K-step: compute on (cK,cV); optionally stage next tile into (nK,nV)
  auto step = [&](const unsigned char* cK, const unsigned char* cV,
                  bool doStage, unsigned char* nK, unsigned char* nV) {
    bf16x8 pf[2][4];   // [tq][kc_global] P in B-operand layout

    // phase 1: QK tk=0 (kk rows [0,32), swizzle baseA); c=0 peeled with zero C
    floatx16 sA0, sA1;
    {
      int p0 = e ^ baseA;
      bf16x8 ka0 = *(const bf16x8*)(cK + (l31 * 8 + p0) * 16);
      sA0 = __builtin_amdgcn_mfma_f32_32x32x16_bf16(ka0, qf[0][0], fz, 0, 0, 0);
      sA1 = __builtin_amdgcn_mfma_f32_32x32x16_bf16(ka0, qf[1][0], fz, 0, 0, 0);
#pragma unroll
      for (int c = 1; c < 4; c++) {
        int p = (2 * c + e) ^ baseA;
        bf16x8 ka = *(const bf16x8*)(cK + (l31 * 8 + p) * 16);
        sA0 = __builtin_amdgcn_mfma_f32_32x32x16_bf16(ka, qf[0][c], sA0, 0, 0, 0);
        sA1 = __builtin_amdgcn_mfma_f32_32x32x16_bf16(ka, qf[1][c], sA1, 0, 0, 0);
      }
    }

    // prefetch next tile now: addressing VALU is just 4 pointer bumps; loads
    // get the remaining ~3/4 of the step to land.
    if (doStage) stage(nK, nV);

    // phase 2: QK tk=1 (kk rows [32,64), swizzle baseB)  -- matrix pipe
    floatx16 sB0, sB1;
    {
      int p0 = e ^ baseB;
      bf16x8 kb0 = *(const bf16x8*)(cK + ((l31 + 32) * 8 + p0) * 16);
      sB0 = __builtin_amdgcn_mfma_f32_32x32x16_bf16(kb0, qf[0][0], fz, 0, 0, 0);
      sB1 = __builtin_amdgcn_mfma_f32_32x32x16_bf16(kb0, qf[1][0], fz, 0, 0, 0);
#pragma unroll
      for (int c = 1; c < 4; c++) {
        int p = (2 * c + e) ^ baseB;
        bf16x8 kb = *(const bf16x8*)(cK + ((l31 + 32) * 8 + p) * 16);
        sB0 = __builtin_amdgcn_mfma_f32_32x32x16_bf16(kb, qf[0][c], sB0, 0, 0, 0);
        sB1 = __builtin_amdgcn_mfma_f32_32x32x16_bf16(kb, qf[1][c], sB1, 0, 0, 0);
      }
    }

    // phase 3: softmax tk=0 (VALU -- overlaps phase-2 MFMAs)
    softmax_half(sA0, 0, 0, pf);
    softmax_half(sA1, 1, 0, pf);

    // phase 4: PV kc=0,1 (uses pf[*][0..1] only)  -- matrix pipe
#pragma unroll
    for (int kc = 0; kc < 2; kc++) {
      int pA = (2 * kc + e) ^ baseA;
      int pB = (2 * kc + e) ^ baseB;
      bf16x8 va = *(const bf16x8*)(cV + (l31 * 8 + pA) * 16);
      bf16x8 vb = *(const bf16x8*)(cV + ((l31 + 32) * 8 + pB) * 16);
      o[0][0] = __builtin_amdgcn_mfma_f32_32x32x16_bf16(va, pf[0][kc], o[0][0], 0, 0, 0);
      o[0][1] = __builtin_amdgcn_mfma_f32_32x32x16_bf16(vb, pf[0][kc], o[0][1], 0, 0, 0);
      o[1][0] = __builtin_amdgcn_mfma_f32_32x32x16_bf16(va, pf[1][kc], o[1][0], 0, 0, 0);
      o[1][1] = __builtin_amdgcn_mfma_f32_32x32x16_bf16(vb, pf[1][kc], o[1][1], 0, 0, 0);
    }

    // phase 5: softmax tk=1 (VALU -- overlaps phase-4 MFMAs)
    softmax_half(sB0, 0, 1, pf);
    softmax_half(sB1, 1, 1, pf);

    // phase 6: PV kc=2,3
#pragma unroll
    for (int kc = 2; kc < 4; kc++) {
      int pA = (2 * kc + e) ^ baseA;
      int pB = (2 * kc + e) ^ baseB;
      bf16x8 va = *(const bf16x8*)(cV + (l31 * 8 + pA) * 16);
      bf16x8 vb = *(const bf16x8*)(cV + ((l31 + 32) * 8 + pB) * 16);
      o[0][0] = __builtin_amdgcn_mfma_f32_32x32x16_bf16(va, pf[0][kc], o[0][0], 0, 0, 0);
      o[0][1] = __builtin_amdgcn_mfma_f32_32x32x16_bf16(vb, pf[0][kc], o[0][1], 0, 0, 0);
      o[1][0] = __builtin_amdgcn_mfma_f32_32x32x16_bf16(va, pf[1][kc], o[1][0], 0, 0, 0);
      o[1][1] = __builtin_amdgcn_mfma_f32_32x32x16_bf16(vb, pf[1][kc], o[1][1], 0, 0, 0);
    }
  };

  // prologue: stage tile 0 into buffer 0
  stage(sK[0], sV[0]);

  // main loop, manually unrolled by 2 so buffers are compile-time
  for (int st = 0; st < NSTEP; st += 2) {
    __syncthreads();                        // buf0 ready; buf1 free
    step(sK[0], sV[0], true, sK[1], sV[1]); // stages tile st+1 (st+1<=15 always)
    __syncthreads();                        // buf1 ready; buf0 free
    step(sK[1], sV[1], st + 2 < NSTEP, sK[0], sV[0]);  // stages tile st+2
  }

  // epilogue: store split numerators (bf16) + denominators (f32)
#pragma unroll
  for (int tq = 0; tq < 2; tq++) {
    float l = ls[tq];
    l += __shfl_xor(l, 32, 64);
    int qrow = q0 + 32 * tq + l31;
    unsigned short* op = Op + (((ks * 16 + h) * SQ) + qrow) * DD;
#pragma unroll
    for (int t4 = 0; t4 < 4; t4++) {
      uint2 a, b;
      a.x = pack_bf2(o[tq][0][4 * t4 + 0], o[tq][0][4 * t4 + 1]);
      a.y = pack_bf2(o[tq][0][4 * t4 + 2], o[tq][0][4 * t4 + 3]);
      b.x = pack_bf2(o[tq][1][4 * t4 + 0], o[tq][1][4 * t4 + 1]);
      b.y = pack_bf2(o[tq][1][4 * t4 + 2], o[tq][1][4 * t4 + 3]);
      *(uint2*)(op + 8 * t4 + 4 * e) = a;         // d = 8t4+4e+0..3
      *(uint2*)(op + 32 + 8 * t4 + 4 * e) = b;    // d = 32+8t4+4e+0..3
    }
    if (e == 0) Lp[(ks * 16 + h) * SQ + qrow] = l;
  }
}

// ---------------- combine splits (bf16 numerators, 8 d per thread) -----------
__global__ __launch_bounds__(256) void combine(const unsigned short* __restrict__ Op,
                                               const float* __restrict__ Lp,
                                               float* __restrict__ out) {
  int idx = blockIdx.x * 256 + threadIdx.x;     // 131072 threads
  int d8 = idx & 7, q = (idx >> 3) & 1023, h = idx >> 13;
  float num[8] = {0.f, 0.f, 0.f, 0.f, 0.f, 0.f, 0.f, 0.f};
  float den = 0.f;
#pragma unroll
  for (int s = 0; s < KSPLIT; s++) {
    int row = (s * 16 + h) * SQ + q;
    uint4 pkv = *(const uint4*)(Op + row * DD + 8 * d8);
    num[0] += __builtin_bit_cast(float, pkv.x << 16);
    num[1] += __builtin_bit_cast(float, pkv.x & 0xffff0000u);
    num[2] += __builtin_bit_cast(float, pkv.y << 16);
    num[3] += __builtin_bit_cast(float, pkv.y & 0xffff0000u);
    num[4] += __builtin_bit_cast(float, pkv.z << 16);
    num[5] += __builtin_bit_cast(float, pkv.z & 0xffff0000u);
    num[6] += __builtin_bit_cast(float, pkv.w << 16);
    num[7] += __builtin_bit_cast(float, pkv.w & 0xffff0000u);
    den += Lp[row];
  }
  float r = 1.0f / den;
  float* op = out + q * (HH * DD) + h * DD + 8 * d8;
  float4 a, bq;
  a.x = num[0] * r; a.y = num[1] * r; a.z = num[2] * r; a.w = num[3] * r;
  bq.x = num[4] * r; bq.y = num[5] * r; bq.z = num[6] * r; bq.w = num[7] * r;
  *(float4*)(op) = a;
  *(float4*)(op + 4) = bq;
}

extern "C" void kernel_launch(void* const* d_in, const int* in_sizes, int n_in,
                              void* d_out, int out_size, void* d_ws, size_t ws_size,
                              hipStream_t stream) {
  const float* q  = (const float*)d_in[0];
  const float* k  = (const float*)d_in[1];
  const float* v  = (const float*)d_in[2];
  const float* ck = (const float*)d_in[3];
  const float* cv = (const float*)d_in[4];
  const float* fc = (const float*)d_in[5];
  const float* fs = (const float*)d_in[6];
  float* out = (float*)d_out;
  char* ws = (char*)d_ws;

  unsigned short* Kb = (unsigned short*)(ws + KB_OFF);
  unsigned short* Vt = (unsigned short*)(ws + VT_OFF);
  unsigned short* Qb = (unsigned short*)(ws + QB_OFF);
  unsigned short* Op = (unsigned short*)(ws + OP_OFF);
  float* Lp = (float*)(ws + LP_OFF);

  prepass<<<3840, 256, 0, stream>>>(q, k, v, ck, cv, fc, fs, Kb, Vt, Qb);
  attn<<<512, 256, 0, stream>>>(Kb, Vt, Qb, Op, Lp);
  combine<<<512, 256, 0, stream>>>(Op, Lp, out);
}